// Round 2
// baseline (729.627 us; speedup 1.0000x reference)
//
#include <hip/hip_runtime.h>
#include <stdint.h>

#define N_NODES 50000
#define N_EDGES 800000
#define EMB 128
#define NPAD 50048        // padded to multiple of 64 rows for MLP tiles
#define BN_EPS 1e-5f

typedef __attribute__((ext_vector_type(8))) short short8;
typedef __attribute__((ext_vector_type(4))) float f32x4;

__device__ __forceinline__ float bf2f(unsigned short u) {
    return __uint_as_float(((unsigned int)u) << 16);
}
__device__ __forceinline__ unsigned short f2bf(float f) {
    unsigned int u = __float_as_uint(f);
    u += 0x7fffu + ((u >> 16) & 1u);   // RNE; values finite
    return (unsigned short)(u >> 16);
}
__device__ __forceinline__ float bflo(unsigned int v) { return __uint_as_float(v << 16); }
__device__ __forceinline__ float bfhi(unsigned int v) { return __uint_as_float(v & 0xffff0000u); }
__device__ __forceinline__ unsigned int packbf(float lo, float hi) {
    return (unsigned int)f2bf(lo) | ((unsigned int)f2bf(hi) << 16);
}

// ---------------- embedding: h[i][d] = xemb1[x[i,0]][d] + xemb2[x[i,1]][d]  (fp32 in, bf16x2 out) ----
__global__ void k_embed(const int* __restrict__ x, const float* __restrict__ xe1,
                        const float* __restrict__ xe2, unsigned int* __restrict__ h) {
    int idx = blockIdx.x * 256 + threadIdx.x;   // [0, N*64)
    int i = idx >> 6, j = idx & 63;
    if (i >= N_NODES) return;
    int a = x[2 * i], c = x[2 * i + 1];
    float2 va = *(const float2*)(xe1 + a * EMB + j * 2);
    float2 vb = *(const float2*)(xe2 + c * EMB + j * 2);
    h[i * 64 + j] = packbf(va.x + vb.x, va.y + vb.y);
}

__global__ void k_zero(unsigned int* __restrict__ p, int n) {
    int i = blockIdx.x * 256 + threadIdx.x;
    if (i < n) p[i] = 0u;
}

// ---------------- CSR build ----------------
__global__ void k_hist(const int* __restrict__ dst, int* __restrict__ deg) {
    int e = blockIdx.x * 256 + threadIdx.x;
    if (e < N_EDGES) atomicAdd(&deg[dst[e]], 1);
}

__global__ void k_scan1(const int* __restrict__ deg, int* __restrict__ part, int* __restrict__ bsums) {
    __shared__ int sm[1024];
    int i = blockIdx.x * 1024 + threadIdx.x;
    int v = (i < N_NODES) ? deg[i] : 0;
    sm[threadIdx.x] = v;
    __syncthreads();
    for (int off = 1; off < 1024; off <<= 1) {
        int t = (threadIdx.x >= off) ? sm[threadIdx.x - off] : 0;
        __syncthreads();
        sm[threadIdx.x] += t;
        __syncthreads();
    }
    if (i < N_NODES) part[i] = sm[threadIdx.x] - v;   // exclusive within block
    if (threadIdx.x == 1023) bsums[blockIdx.x] = sm[1023];
}

__global__ void k_scan2(int* __restrict__ bsums, int nb) {
    if (threadIdx.x == 0 && blockIdx.x == 0) {
        int acc = 0;
        for (int b = 0; b < nb; ++b) { int t = bsums[b]; bsums[b] = acc; acc += t; }
    }
}

__global__ void k_scan3(int* __restrict__ part, const int* __restrict__ bsums, int* __restrict__ cursor) {
    int i = blockIdx.x * 256 + threadIdx.x;
    if (i >= N_NODES) return;
    int o = part[i] + bsums[i >> 10];
    part[i] = o;
    cursor[i] = o;
}

__global__ void k_fill(const int* __restrict__ dst, int* __restrict__ cursor, int* __restrict__ csr) {
    int e = blockIdx.x * 256 + threadIdx.x;
    if (e >= N_EDGES) return;
    int p = atomicAdd(&cursor[dst[e]], 1);
    csr[p] = e;
}

// ---------------- weight transpose+cast (once per call): out[c*R+r] = bf16(in[r*C+c]) ----------------
__global__ void k_transpose(const float* __restrict__ in, unsigned short* __restrict__ out,
                            int R, int C) {
    int idx = blockIdx.x * 256 + threadIdx.x;
    if (idx >= R * C) return;
    int r = idx / C, c = idx - r * C;
    out[c * R + r] = f2bf(in[idx]);
}

// ---------------- aggregation: one wave per node, lane = 2 features ----------------
__global__ __launch_bounds__(256) void k_agg(
    const unsigned int* __restrict__ h,        // [N][64] packed bf16x2
    const int* __restrict__ src, const int* __restrict__ ea,
    const int* __restrict__ offs, const int* __restrict__ deg, const int* __restrict__ csr,
    const float* __restrict__ e1l, const float* __restrict__ e2l,
    unsigned int* __restrict__ agg)            // [NPAD][64] packed bf16x2
{
    __shared__ float2 e12[21 * 64];            // e1[a0]+e2[a1] combined table (a0<7, a1<3)
    for (int t = threadIdx.x; t < 21 * 64; t += 256) {
        int combo = t >> 6, f = t & 63;
        int a0 = combo / 3, a1 = combo - a0 * 3;
        float2 v;
        v.x = e1l[a0 * EMB + 2 * f]     + e2l[a1 * EMB + 2 * f];
        v.y = e1l[a0 * EMB + 2 * f + 1] + e2l[a1 * EMB + 2 * f + 1];
        e12[t] = v;
    }
    __syncthreads();
    int wave = threadIdx.x >> 6, lane = threadIdx.x & 63;
    int node = blockIdx.x * 4 + wave;
    float ax = 0.f, ay = 0.f;
    if (node < N_NODES) {
        // self loop: attr = [4,0] -> combo 12
        unsigned int hv = h[node * 64 + lane];
        float2 sv = e12[12 * 64 + lane];
        ax = bflo(hv) + sv.x;
        ay = bfhi(hv) + sv.y;
        int o = offs[node], d = deg[node];
        for (int k = o; k < o + d; ++k) {
            int e = csr[k];
            int s = src[e];
            int a0 = ea[2 * e], a1 = ea[2 * e + 1];
            unsigned int g = h[s * 64 + lane];
            float2 ev = e12[(a0 * 3 + a1) * 64 + lane];
            ax += bflo(g) + ev.x;
            ay += bfhi(g) + ev.y;
        }
    }
    if (node < NPAD) agg[node * 64 + lane] = packbf(ax, ay);   // pad rows -> zeros
}

// ---------------- fused MLP: h2 = relu(agg@W1+b1)@W2+b2 ----------------
// h2 aliases agg (same buffer): each block reads only its own 64 rows and all
// reads complete (via the LDS round-trip) before its stores. No __restrict__.
__global__ __launch_bounds__(256) void k_mlp(
    unsigned short* aggh2,                     // [NPAD][128] bf16 in, [N][128] bf16 out
    const unsigned short* __restrict__ w1t,    // [256][128]  (W1 transposed: [n][k])
    const float* __restrict__ b1,              // [256]
    const unsigned short* __restrict__ w2t,    // [128][256]  (W2 transposed: [n][k])
    const float* __restrict__ b2)              // [128]
{
    __shared__ __align__(16) short tl[4][16][264];   // per-wave 16x256 t tile, padded stride
    int wave = threadIdx.x >> 6, lane = threadIdx.x & 63;
    int quad = lane >> 4, r16 = lane & 15;
    int m0 = (blockIdx.x * 4 + wave) * 16;

    // A fragments for GEMM1: A[m=r16][k=quad*8+j], 4 K-chunks of 32
    const unsigned short* arow = aggh2 + (size_t)(m0 + r16) * 128 + quad * 8;
    short8 af[4];
#pragma unroll
    for (int c = 0; c < 4; ++c) af[c] = *(const short8*)(arow + c * 32);

    // GEMM1 + bias + relu -> LDS
#pragma unroll
    for (int nt = 0; nt < 16; ++nt) {
        f32x4 acc = {0.f, 0.f, 0.f, 0.f};
        const unsigned short* brow = w1t + (nt * 16 + r16) * 128 + quad * 8;
#pragma unroll
        for (int c = 0; c < 4; ++c)
            acc = __builtin_amdgcn_mfma_f32_16x16x32_bf16(af[c], *(const short8*)(brow + c * 32), acc, 0, 0, 0);
        float bv = b1[nt * 16 + r16];   // bias along col = r16
#pragma unroll
        for (int r = 0; r < 4; ++r) {
            float v = acc[r] + bv;
            v = v > 0.f ? v : 0.f;
            tl[wave][quad * 4 + r][nt * 16 + r16] = (short)f2bf(v);
        }
    }
    __syncthreads();

    // GEMM2: A = t (LDS), 8 K-chunks of 32 over K=256, 8 N-tiles over 128
    f32x4 acc2[8];
#pragma unroll
    for (int nt = 0; nt < 8; ++nt) acc2[nt] = (f32x4){0.f, 0.f, 0.f, 0.f};
#pragma unroll
    for (int c2 = 0; c2 < 8; ++c2) {
        short8 a2 = *(const short8*)(&tl[wave][r16][c2 * 32 + quad * 8]);
#pragma unroll
        for (int nt = 0; nt < 8; ++nt) {
            short8 bfrag = *(const short8*)(w2t + (nt * 16 + r16) * 256 + c2 * 32 + quad * 8);
            acc2[nt] = __builtin_amdgcn_mfma_f32_16x16x32_bf16(a2, bfrag, acc2[nt], 0, 0, 0);
        }
    }
#pragma unroll
    for (int nt = 0; nt < 8; ++nt) {
        float bv = b2[nt * 16 + r16];
#pragma unroll
        for (int r = 0; r < 4; ++r) {
            int row = m0 + quad * 4 + r;
            if (row < N_NODES) aggh2[(size_t)row * 128 + nt * 16 + r16] = f2bf(acc2[nt][r] + bv);
        }
    }
}

// ---------------- BN stats: per-column sum & sumsq (fp32) ----------------
__global__ void k_bnstats(const unsigned int* __restrict__ h2, float* __restrict__ cs) {
    int p = threadIdx.x & 63;                  // column pair
    int half = threadIdx.x >> 6;               // 0..3
    int r0 = blockIdx.x * 500;                 // 100 blocks x 500 rows = 50000
    float s0 = 0.f, s1 = 0.f, q0 = 0.f, q1 = 0.f;
    for (int r = r0 + half; r < r0 + 500; r += 4) {
        unsigned int v = h2[(size_t)r * 64 + p];
        float a = bflo(v), b = bfhi(v);
        s0 += a; q0 += a * a;
        s1 += b; q1 += b * b;
    }
    atomicAdd(&cs[2 * p], s0);
    atomicAdd(&cs[2 * p + 1], s1);
    atomicAdd(&cs[128 + 2 * p], q0);
    atomicAdd(&cs[128 + 2 * p + 1], q1);
}

// ---------------- BN normalize (+relu for layer 0 -> bf16 h; layer 1 -> fp32 d_out) ----------------
__global__ void k_bnnorm(const unsigned int* __restrict__ h2, const float* __restrict__ cs,
                         const float* __restrict__ gamma, const float* __restrict__ beta,
                         unsigned int* __restrict__ outb, float2* __restrict__ outf, int mode) {
    int idx = blockIdx.x * 256 + threadIdx.x;  // [0, N*64)
    if (idx >= N_NODES * 64) return;
    int p = idx & 63;
    int c0 = 2 * p, c1 = 2 * p + 1;
    float m0 = cs[c0] * (1.f / N_NODES);
    float m1 = cs[c1] * (1.f / N_NODES);
    float v0 = cs[128 + c0] * (1.f / N_NODES) - m0 * m0;
    float v1 = cs[128 + c1] * (1.f / N_NODES) - m1 * m1;
    float r0 = rsqrtf(v0 + BN_EPS), r1 = rsqrtf(v1 + BN_EPS);
    unsigned int hv = h2[idx];
    float a = (bflo(hv) - m0) * r0 * gamma[c0] + beta[c0];
    float b = (bfhi(hv) - m1) * r1 * gamma[c1] + beta[c1];
    if (mode == 0) {
        a = a > 0.f ? a : 0.f;
        b = b > 0.f ? b : 0.f;
        outb[idx] = packbf(a, b);
    } else {
        outf[idx] = make_float2(a, b);
    }
}

extern "C" void kernel_launch(void* const* d_in, const int* in_sizes, int n_in,
                              void* d_out, int out_size, void* d_ws, size_t ws_size,
                              hipStream_t stream) {
    const int* x  = (const int*)d_in[0];
    const int* ei = (const int*)d_in[1];
    const int* ea = (const int*)d_in[2];
    // d_in[3] = batch (unused)
    const float* xe1 = (const float*)d_in[4];
    const float* xe2 = (const float*)d_in[5];
    const float* e1  = (const float*)d_in[6];   // [2][7][128]
    const float* e2  = (const float*)d_in[7];   // [2][3][128]
    const float* W1  = (const float*)d_in[8];   // [2][128][256]
    const float* b1  = (const float*)d_in[9];   // [2][256]
    const float* W2  = (const float*)d_in[10];  // [2][256][128]
    const float* b2  = (const float*)d_in[11];  // [2][128]
    const float* gm  = (const float*)d_in[12];  // [2][128]
    const float* bt  = (const float*)d_in[13];  // [2][128]

    char* ws = (char*)d_ws;
    size_t off = 0;
    auto take = [&](size_t bytes) -> char* {
        char* p = ws + off;
        off = (off + bytes + 255) & ~(size_t)255;
        return p;
    };
    unsigned int* h_buf = (unsigned int*)take((size_t)N_NODES * 64 * 4);   // bf16x2 packed
    unsigned int* aggb  = (unsigned int*)take((size_t)NPAD * 64 * 4);      // agg, then h2 (aliased)
    unsigned short* w1t = (unsigned short*)take((size_t)2 * 32768 * 2);
    unsigned short* w2t = (unsigned short*)take((size_t)2 * 32768 * 2);
    int* deg    = (int*)take((size_t)N_NODES * 4);
    int* offs   = (int*)take((size_t)N_NODES * 4);
    int* cursor = (int*)take((size_t)N_NODES * 4);
    int* csr    = (int*)take((size_t)N_EDGES * 4);
    int* bsums  = (int*)take(64 * 4);
    float* cs   = (float*)take(256 * 4);

    const int* srcs = ei;
    const int* dsts = ei + N_EDGES;

    k_embed<<<(N_NODES * 64) / 256, 256, 0, stream>>>(x, xe1, xe2, h_buf);
    k_zero<<<(N_NODES + 255) / 256, 256, 0, stream>>>((unsigned int*)deg, N_NODES);
    k_hist<<<(N_EDGES + 255) / 256, 256, 0, stream>>>(dsts, deg);
    k_scan1<<<49, 1024, 0, stream>>>(deg, offs, bsums);
    k_scan2<<<1, 64, 0, stream>>>(bsums, 49);
    k_scan3<<<(N_NODES + 255) / 256, 256, 0, stream>>>(offs, bsums, cursor);
    k_fill<<<(N_EDGES + 255) / 256, 256, 0, stream>>>(dsts, cursor, csr);
    k_transpose<<<128, 256, 0, stream>>>(W1, w1t, 128, 256);
    k_transpose<<<128, 256, 0, stream>>>(W1 + 32768, w1t + 32768, 128, 256);
    k_transpose<<<128, 256, 0, stream>>>(W2, w2t, 256, 128);
    k_transpose<<<128, 256, 0, stream>>>(W2 + 32768, w2t + 32768, 256, 128);

    for (int l = 0; l < 2; ++l) {
        k_agg<<<NPAD / 4, 256, 0, stream>>>(h_buf, srcs, ea, offs, deg, csr,
                                            e1 + l * 896, e2 + l * 384, aggb);
        k_mlp<<<NPAD / 64, 256, 0, stream>>>((unsigned short*)aggb, w1t + l * 32768, b1 + l * 256,
                                             w2t + l * 32768, b2 + l * 128);
        k_zero<<<1, 256, 0, stream>>>((unsigned int*)cs, 256);
        k_bnstats<<<100, 256, 0, stream>>>(aggb, cs);
        k_bnnorm<<<(N_NODES * 64) / 256, 256, 0, stream>>>(aggb, cs, gm + l * 128, bt + l * 128,
                                                           h_buf, (float2*)d_out, l);
    }
}

// Round 3
// 567.440 us; speedup vs baseline: 1.2858x; 1.2858x over previous
//
#include <hip/hip_runtime.h>
#include <stdint.h>

#define N_NODES 50000
#define N_EDGES 800000
#define EMB 128
#define NPAD 50048        // padded to multiple of 64 rows for MLP tiles
#define BN_EPS 1e-5f

typedef __attribute__((ext_vector_type(8))) short short8;
typedef __attribute__((ext_vector_type(4))) float f32x4;

__device__ __forceinline__ float bf2f(unsigned short u) {
    return __uint_as_float(((unsigned int)u) << 16);
}
__device__ __forceinline__ unsigned short f2bf(float f) {
    unsigned int u = __float_as_uint(f);
    u += 0x7fffu + ((u >> 16) & 1u);   // RNE; values finite
    return (unsigned short)(u >> 16);
}
__device__ __forceinline__ float bflo(unsigned int v) { return __uint_as_float(v << 16); }
__device__ __forceinline__ float bfhi(unsigned int v) { return __uint_as_float(v & 0xffff0000u); }
__device__ __forceinline__ unsigned int packbf(float lo, float hi) {
    return (unsigned int)f2bf(lo) | ((unsigned int)f2bf(hi) << 16);
}

// ---------------- embedding: h[i][d] = xemb1[x[i,0]][d] + xemb2[x[i,1]][d]  (fp32 in, bf16x2 out) ----
__global__ void k_embed(const int* __restrict__ x, const float* __restrict__ xe1,
                        const float* __restrict__ xe2, unsigned int* __restrict__ h) {
    int idx = blockIdx.x * 256 + threadIdx.x;   // [0, N*64)
    int i = idx >> 6, j = idx & 63;
    if (i >= N_NODES) return;
    int a = x[2 * i], c = x[2 * i + 1];
    float2 va = *(const float2*)(xe1 + a * EMB + j * 2);
    float2 vb = *(const float2*)(xe2 + c * EMB + j * 2);
    h[i * 64 + j] = packbf(va.x + vb.x, va.y + vb.y);
}

__global__ void k_zero(unsigned int* __restrict__ p, int n) {
    int i = blockIdx.x * 256 + threadIdx.x;
    if (i < n) p[i] = 0u;
}

// ---------------- CSR build ----------------
__global__ void k_hist(const int* __restrict__ dst, int* __restrict__ deg) {
    int e = blockIdx.x * 256 + threadIdx.x;
    if (e < N_EDGES) atomicAdd(&deg[dst[e]], 1);
}

__global__ void k_scan1(const int* __restrict__ deg, int* __restrict__ part, int* __restrict__ bsums) {
    __shared__ int sm[1024];
    int i = blockIdx.x * 1024 + threadIdx.x;
    int v = (i < N_NODES) ? deg[i] : 0;
    sm[threadIdx.x] = v;
    __syncthreads();
    for (int off = 1; off < 1024; off <<= 1) {
        int t = (threadIdx.x >= off) ? sm[threadIdx.x - off] : 0;
        __syncthreads();
        sm[threadIdx.x] += t;
        __syncthreads();
    }
    if (i < N_NODES) part[i] = sm[threadIdx.x] - v;   // exclusive within block
    if (threadIdx.x == 1023) bsums[blockIdx.x] = sm[1023];
}

// one-wave shuffle prefix scan over <=64 block sums
__global__ void k_scan2(int* __restrict__ bsums, int nb) {
    int lane = threadIdx.x;
    int v = (lane < nb) ? bsums[lane] : 0;
    int orig = v;
    for (int off = 1; off < 64; off <<= 1) {
        int t = __shfl_up(v, off);
        if (lane >= off) v += t;
    }
    if (lane < nb) bsums[lane] = v - orig;   // exclusive
}

__global__ void k_scan3(int* __restrict__ part, const int* __restrict__ bsums, int* __restrict__ cursor) {
    int i = blockIdx.x * 256 + threadIdx.x;
    if (i >= N_NODES) return;
    int o = part[i] + bsums[i >> 10];
    part[i] = o;
    cursor[i] = o;
}

__global__ void k_fill(const int* __restrict__ dst, int* __restrict__ cursor, int* __restrict__ csr) {
    int e = blockIdx.x * 256 + threadIdx.x;
    if (e >= N_EDGES) return;
    int p = atomicAdd(&cursor[dst[e]], 1);
    csr[p] = e;
}

// ---------------- weight transpose+cast (once per call): out[c*R+r] = bf16(in[r*C+c]) ----------------
__global__ void k_transpose(const float* __restrict__ in, unsigned short* __restrict__ out,
                            int R, int C) {
    int idx = blockIdx.x * 256 + threadIdx.x;
    if (idx >= R * C) return;
    int r = idx / C, c = idx - r * C;
    out[c * R + r] = f2bf(in[idx]);
}

// ---------------- aggregation: one wave per node, lane = 2 features ----------------
// Edge metadata is loaded 64-edges-at-a-time across lanes (coalesced), then the
// inner loop shfl-broadcasts packed keys so the h-row gathers are independent
// loads the scheduler can keep in flight (MLP), instead of a serial 3-deep
// dependent-load chain per edge.
__global__ __launch_bounds__(256) void k_agg(
    const unsigned int* __restrict__ h,        // [N][64] packed bf16x2
    const int* __restrict__ src, const int* __restrict__ ea,
    const int* __restrict__ offs, const int* __restrict__ deg, const int* __restrict__ csr,
    const float* __restrict__ e1l, const float* __restrict__ e2l,
    unsigned int* __restrict__ agg)            // [NPAD][64] packed bf16x2
{
    __shared__ float2 e12[21 * 64];            // e1[a0]+e2[a1] combined table (a0<7, a1<3)
    for (int t = threadIdx.x; t < 21 * 64; t += 256) {
        int combo = t >> 6, f = t & 63;
        int a0 = combo / 3, a1 = combo - a0 * 3;
        float2 v;
        v.x = e1l[a0 * EMB + 2 * f]     + e2l[a1 * EMB + 2 * f];
        v.y = e1l[a0 * EMB + 2 * f + 1] + e2l[a1 * EMB + 2 * f + 1];
        e12[t] = v;
    }
    __syncthreads();
    int wave = threadIdx.x >> 6, lane = threadIdx.x & 63;
    int node = blockIdx.x * 4 + wave;
    float ax = 0.f, ay = 0.f;
    if (node < N_NODES) {
        // self loop: attr = [4,0] -> combo 12
        unsigned int hv = h[node * 64 + lane];
        float2 sv = e12[12 * 64 + lane];
        ax = bflo(hv) + sv.x;
        ay = bfhi(hv) + sv.y;
        int o = offs[node], d = deg[node];
        for (int base = 0; base < d; base += 64) {
            int cnt = min(d - base, 64);
            int key = 0;
            if (lane < cnt) {
                int e = csr[o + base + lane];
                int s = src[e];
                int a0 = ea[2 * e], a1 = ea[2 * e + 1];
                key = (s << 5) | (a0 * 3 + a1);    // s < 2^17, combo < 21
            }
#pragma unroll 4
            for (int j = 0; j < cnt; ++j) {
                int kj = __shfl(key, j);
                unsigned int g = h[(kj >> 5) * 64 + lane];
                float2 ev = e12[(kj & 31) * 64 + lane];
                ax += bflo(g) + ev.x;
                ay += bfhi(g) + ev.y;
            }
        }
    }
    if (node < NPAD) agg[node * 64 + lane] = packbf(ax, ay);   // pad rows -> zeros
}

// ---------------- fused MLP: h2 = relu(agg@W1+b1)@W2+b2 ----------------
// h2 aliases agg (same buffer): each block reads only its own 64 rows and all
// reads complete (via the LDS round-trip) before its stores. No __restrict__.
__global__ __launch_bounds__(256) void k_mlp(
    unsigned short* aggh2,                     // [NPAD][128] bf16 in, [N][128] bf16 out
    const unsigned short* __restrict__ w1t,    // [256][128]  (W1 transposed: [n][k])
    const float* __restrict__ b1,              // [256]
    const unsigned short* __restrict__ w2t,    // [128][256]  (W2 transposed: [n][k])
    const float* __restrict__ b2)              // [128]
{
    __shared__ __align__(16) short tl[4][16][264];   // per-wave 16x256 t tile, padded stride
    int wave = threadIdx.x >> 6, lane = threadIdx.x & 63;
    int quad = lane >> 4, r16 = lane & 15;
    int m0 = (blockIdx.x * 4 + wave) * 16;

    // A fragments for GEMM1: A[m=r16][k=quad*8+j], 4 K-chunks of 32
    const unsigned short* arow = aggh2 + (size_t)(m0 + r16) * 128 + quad * 8;
    short8 af[4];
#pragma unroll
    for (int c = 0; c < 4; ++c) af[c] = *(const short8*)(arow + c * 32);

    // GEMM1 + bias + relu -> LDS
#pragma unroll
    for (int nt = 0; nt < 16; ++nt) {
        f32x4 acc = {0.f, 0.f, 0.f, 0.f};
        const unsigned short* brow = w1t + (nt * 16 + r16) * 128 + quad * 8;
#pragma unroll
        for (int c = 0; c < 4; ++c)
            acc = __builtin_amdgcn_mfma_f32_16x16x32_bf16(af[c], *(const short8*)(brow + c * 32), acc, 0, 0, 0);
        float bv = b1[nt * 16 + r16];   // bias along col = r16
#pragma unroll
        for (int r = 0; r < 4; ++r) {
            float v = acc[r] + bv;
            v = v > 0.f ? v : 0.f;
            tl[wave][quad * 4 + r][nt * 16 + r16] = (short)f2bf(v);
        }
    }
    __syncthreads();

    // GEMM2: A = t (LDS), 8 K-chunks of 32 over K=256, 8 N-tiles over 128
    f32x4 acc2[8];
#pragma unroll
    for (int nt = 0; nt < 8; ++nt) acc2[nt] = (f32x4){0.f, 0.f, 0.f, 0.f};
#pragma unroll
    for (int c2 = 0; c2 < 8; ++c2) {
        short8 a2 = *(const short8*)(&tl[wave][r16][c2 * 32 + quad * 8]);
#pragma unroll
        for (int nt = 0; nt < 8; ++nt) {
            short8 bfrag = *(const short8*)(w2t + (nt * 16 + r16) * 256 + c2 * 32 + quad * 8);
            acc2[nt] = __builtin_amdgcn_mfma_f32_16x16x32_bf16(a2, bfrag, acc2[nt], 0, 0, 0);
        }
    }
#pragma unroll
    for (int nt = 0; nt < 8; ++nt) {
        float bv = b2[nt * 16 + r16];
#pragma unroll
        for (int r = 0; r < 4; ++r) {
            int row = m0 + quad * 4 + r;
            if (row < N_NODES) aggh2[(size_t)row * 128 + nt * 16 + r16] = f2bf(acc2[nt][r] + bv);
        }
    }
}

// ---------------- BN stats: per-column sum & sumsq (fp32), LDS-reduced, 250 blocks ----------------
__global__ void k_bnstats(const unsigned int* __restrict__ h2, float* __restrict__ cs) {
    __shared__ float4 sm[256];
    int p = threadIdx.x & 63;                  // column pair
    int g = threadIdx.x >> 6;                  // 0..3
    int r0 = blockIdx.x * 200;                 // 250 blocks x 200 rows = 50000
    float s0 = 0.f, s1 = 0.f, q0 = 0.f, q1 = 0.f;
    for (int r = r0 + g; r < r0 + 200; r += 4) {
        unsigned int v = h2[(size_t)r * 64 + p];
        float a = bflo(v), b = bfhi(v);
        s0 += a; q0 += a * a;
        s1 += b; q1 += b * b;
    }
    sm[threadIdx.x] = make_float4(s0, s1, q0, q1);
    __syncthreads();
    if (threadIdx.x < 64) {
        float4 a = sm[p], b = sm[p + 64], c = sm[p + 128], d = sm[p + 192];
        atomicAdd(&cs[2 * p],       a.x + b.x + c.x + d.x);
        atomicAdd(&cs[2 * p + 1],   a.y + b.y + c.y + d.y);
        atomicAdd(&cs[128 + 2 * p],     a.z + b.z + c.z + d.z);
        atomicAdd(&cs[128 + 2 * p + 1], a.w + b.w + c.w + d.w);
    }
}

// ---------------- BN normalize (+relu for layer 0 -> bf16 h; layer 1 -> fp32 d_out) ----------------
__global__ void k_bnnorm(const unsigned int* __restrict__ h2, const float* __restrict__ cs,
                         const float* __restrict__ gamma, const float* __restrict__ beta,
                         unsigned int* __restrict__ outb, float2* __restrict__ outf, int mode) {
    int idx = blockIdx.x * 256 + threadIdx.x;  // [0, N*64)
    if (idx >= N_NODES * 64) return;
    int p = idx & 63;
    int c0 = 2 * p, c1 = 2 * p + 1;
    float m0 = cs[c0] * (1.f / N_NODES);
    float m1 = cs[c1] * (1.f / N_NODES);
    float v0 = cs[128 + c0] * (1.f / N_NODES) - m0 * m0;
    float v1 = cs[128 + c1] * (1.f / N_NODES) - m1 * m1;
    float r0 = rsqrtf(v0 + BN_EPS), r1 = rsqrtf(v1 + BN_EPS);
    unsigned int hv = h2[idx];
    float a = (bflo(hv) - m0) * r0 * gamma[c0] + beta[c0];
    float b = (bfhi(hv) - m1) * r1 * gamma[c1] + beta[c1];
    if (mode == 0) {
        a = a > 0.f ? a : 0.f;
        b = b > 0.f ? b : 0.f;
        outb[idx] = packbf(a, b);
    } else {
        outf[idx] = make_float2(a, b);
    }
}

extern "C" void kernel_launch(void* const* d_in, const int* in_sizes, int n_in,
                              void* d_out, int out_size, void* d_ws, size_t ws_size,
                              hipStream_t stream) {
    const int* x  = (const int*)d_in[0];
    const int* ei = (const int*)d_in[1];
    const int* ea = (const int*)d_in[2];
    // d_in[3] = batch (unused)
    const float* xe1 = (const float*)d_in[4];
    const float* xe2 = (const float*)d_in[5];
    const float* e1  = (const float*)d_in[6];   // [2][7][128]
    const float* e2  = (const float*)d_in[7];   // [2][3][128]
    const float* W1  = (const float*)d_in[8];   // [2][128][256]
    const float* b1  = (const float*)d_in[9];   // [2][256]
    const float* W2  = (const float*)d_in[10];  // [2][256][128]
    const float* b2  = (const float*)d_in[11];  // [2][128]
    const float* gm  = (const float*)d_in[12];  // [2][128]
    const float* bt  = (const float*)d_in[13];  // [2][128]

    char* ws = (char*)d_ws;
    size_t off = 0;
    auto take = [&](size_t bytes) -> char* {
        char* p = ws + off;
        off = (off + bytes + 255) & ~(size_t)255;
        return p;
    };
    unsigned int* h_buf = (unsigned int*)take((size_t)N_NODES * 64 * 4);   // bf16x2 packed
    unsigned int* aggb  = (unsigned int*)take((size_t)NPAD * 64 * 4);      // agg, then h2 (aliased)
    unsigned short* w1t = (unsigned short*)take((size_t)2 * 32768 * 2);
    unsigned short* w2t = (unsigned short*)take((size_t)2 * 32768 * 2);
    int* deg    = (int*)take((size_t)N_NODES * 4);
    int* offs   = (int*)take((size_t)N_NODES * 4);
    int* cursor = (int*)take((size_t)N_NODES * 4);
    int* csr    = (int*)take((size_t)N_EDGES * 4);
    int* bsums  = (int*)take(64 * 4);
    float* cs   = (float*)take(256 * 4);

    const int* srcs = ei;
    const int* dsts = ei + N_EDGES;

    k_embed<<<(N_NODES * 64) / 256, 256, 0, stream>>>(x, xe1, xe2, h_buf);
    k_zero<<<(N_NODES + 255) / 256, 256, 0, stream>>>((unsigned int*)deg, N_NODES);
    k_hist<<<(N_EDGES + 255) / 256, 256, 0, stream>>>(dsts, deg);
    k_scan1<<<49, 1024, 0, stream>>>(deg, offs, bsums);
    k_scan2<<<1, 64, 0, stream>>>(bsums, 49);
    k_scan3<<<(N_NODES + 255) / 256, 256, 0, stream>>>(offs, bsums, cursor);
    k_fill<<<(N_EDGES + 255) / 256, 256, 0, stream>>>(dsts, cursor, csr);
    k_transpose<<<128, 256, 0, stream>>>(W1, w1t, 128, 256);
    k_transpose<<<128, 256, 0, stream>>>(W1 + 32768, w1t + 32768, 128, 256);
    k_transpose<<<128, 256, 0, stream>>>(W2, w2t, 256, 128);
    k_transpose<<<128, 256, 0, stream>>>(W2 + 32768, w2t + 32768, 256, 128);

    for (int l = 0; l < 2; ++l) {
        k_agg<<<NPAD / 4, 256, 0, stream>>>(h_buf, srcs, ea, offs, deg, csr,
                                            e1 + l * 896, e2 + l * 384, aggb);
        k_mlp<<<NPAD / 64, 256, 0, stream>>>((unsigned short*)aggb, w1t + l * 32768, b1 + l * 256,
                                             w2t + l * 32768, b2 + l * 128);
        k_zero<<<1, 256, 0, stream>>>((unsigned int*)cs, 256);
        k_bnstats<<<250, 256, 0, stream>>>(aggb, cs);
        k_bnnorm<<<(N_NODES * 64) / 256, 256, 0, stream>>>(aggb, cs, gm + l * 128, bt + l * 128,
                                                           h_buf, (float2*)d_out, l);
    }
}

// Round 4
// 487.819 us; speedup vs baseline: 1.4957x; 1.1632x over previous
//
#include <hip/hip_runtime.h>
#include <stdint.h>

#define N_NODES 50000
#define N_EDGES 800000
#define EMB 128
#define NPAD 50048        // padded to multiple of 64 rows for MLP tiles
#define BN_EPS 1e-5f
#define SENT_KEY ((N_NODES << 5) | 21)   // sentinel: zero h-row, zero e12 entry

typedef __attribute__((ext_vector_type(8))) short short8;
typedef __attribute__((ext_vector_type(4))) float f32x4;

__device__ __forceinline__ float bf2f(unsigned short u) {
    return __uint_as_float(((unsigned int)u) << 16);
}
__device__ __forceinline__ unsigned short f2bf(float f) {
    unsigned int u = __float_as_uint(f);
    u += 0x7fffu + ((u >> 16) & 1u);   // RNE; values finite
    return (unsigned short)(u >> 16);
}
__device__ __forceinline__ float bflo(unsigned int v) { return __uint_as_float(v << 16); }
__device__ __forceinline__ float bfhi(unsigned int v) { return __uint_as_float(v & 0xffff0000u); }
__device__ __forceinline__ unsigned int packbf(float lo, float hi) {
    return (unsigned int)f2bf(lo) | ((unsigned int)f2bf(hi) << 16);
}

// ---------------- embedding (fp32 in, bf16x2 out); also writes the zero sentinel row ----------
__global__ void k_embed(const int* __restrict__ x, const float* __restrict__ xe1,
                        const float* __restrict__ xe2, unsigned int* __restrict__ h) {
    int idx = blockIdx.x * 256 + threadIdx.x;   // [0, (N+1)*64)
    int i = idx >> 6, j = idx & 63;
    if (i > N_NODES) return;
    if (i == N_NODES) { h[(size_t)i * 64 + j] = 0u; return; }
    int a = x[2 * i], c = x[2 * i + 1];
    float2 va = *(const float2*)(xe1 + a * EMB + j * 2);
    float2 vb = *(const float2*)(xe2 + c * EMB + j * 2);
    h[i * 64 + j] = packbf(va.x + vb.x, va.y + vb.y);
}

// zero deg[N_NODES] and cs[512] in one launch
__global__ void k_zero2(int* __restrict__ deg, float* __restrict__ cs) {
    int i = blockIdx.x * 256 + threadIdx.x;
    if (i < N_NODES) deg[i] = 0;
    if (i < 512) cs[i] = 0.f;
}

// ---------------- CSR build (padded-to-16 per node, with packed keys) ----------------
__global__ void k_hist(const int* __restrict__ dst, int* __restrict__ deg) {
    int e = blockIdx.x * 256 + threadIdx.x;
    if (e < N_EDGES) atomicAdd(&deg[dst[e]], 1);
}

// scan over PADDED degrees: pdeg = ceil(deg/16)*16
__global__ void k_scan1(const int* __restrict__ deg, int* __restrict__ part, int* __restrict__ bsums) {
    __shared__ int sm[1024];
    int i = blockIdx.x * 1024 + threadIdx.x;
    int d = (i < N_NODES) ? deg[i] : 0;
    int v = (d + 15) & ~15;
    sm[threadIdx.x] = v;
    __syncthreads();
    for (int off = 1; off < 1024; off <<= 1) {
        int t = (threadIdx.x >= off) ? sm[threadIdx.x - off] : 0;
        __syncthreads();
        sm[threadIdx.x] += t;
        __syncthreads();
    }
    if (i < N_NODES) part[i] = sm[threadIdx.x] - v;   // exclusive within block
    if (threadIdx.x == 1023) bsums[blockIdx.x] = sm[1023];
}

// one-wave shuffle prefix scan over <=64 block sums
__global__ void k_scan2(int* __restrict__ bsums, int nb) {
    int lane = threadIdx.x;
    int v = (lane < nb) ? bsums[lane] : 0;
    int orig = v;
    for (int off = 1; off < 64; off <<= 1) {
        int t = __shfl_up(v, off);
        if (lane >= off) v += t;
    }
    if (lane < nb) bsums[lane] = v - orig;   // exclusive
}

__global__ void k_scan3(const int* __restrict__ part, const int* __restrict__ bsums,
                        const int* __restrict__ deg, int* __restrict__ offs,
                        int* __restrict__ cursor) {
    int i = blockIdx.x * 256 + threadIdx.x;
    if (i >= N_NODES) return;
    int o = part[i] + bsums[i >> 10];
    offs[i] = o;
    cursor[i] = o;
    if (i == N_NODES - 1) offs[N_NODES] = o + ((deg[i] + 15) & ~15);
}

// fill packed keys: key = (src<<5) | (a0*3+a1)
__global__ void k_fill(const int* __restrict__ ei, const int* __restrict__ ea,
                       int* __restrict__ cursor, int* __restrict__ keys) {
    int e = blockIdx.x * 256 + threadIdx.x;
    if (e >= N_EDGES) return;
    int d = ei[N_EDGES + e];
    int s = ei[e];
    int a0 = ea[2 * e], a1 = ea[2 * e + 1];
    int p = atomicAdd(&cursor[d], 1);
    keys[p] = (s << 5) | (a0 * 3 + a1);
}

// pad each node's key list up to its padded length with sentinels (pad < 16)
__global__ void k_pad(const int* __restrict__ offs, const int* __restrict__ deg,
                      int* __restrict__ keys) {
    int idx = blockIdx.x * 256 + threadIdx.x;
    int i = idx >> 4, j = idx & 15;
    if (i >= N_NODES) return;
    int p = offs[i] + deg[i] + j;
    if (p < offs[i + 1]) keys[p] = SENT_KEY;
}

// ---------------- fused weight transpose+cast: both layers, both weights ----------------
__global__ void k_transpose4(const float* __restrict__ W1, const float* __restrict__ W2,
                             unsigned short* __restrict__ w1t, unsigned short* __restrict__ w2t) {
    int idx = blockIdx.x * 256 + threadIdx.x;   // [0, 4*32768)
    int sec = idx >> 15, q = idx & 32767;
    if (sec < 2) {           // W1[sec]: [128][256] -> w1t[sec][c*128+r]
        int r = q >> 8, c = q & 255;
        w1t[sec * 32768 + c * 128 + r] = f2bf(W1[sec * 32768 + q]);
    } else {                 // W2[sec-2]: [256][128] -> w2t[sec-2][c*256+r]
        int s = sec - 2;
        int r = q >> 7, c = q & 127;
        w2t[s * 32768 + c * 256 + r] = f2bf(W2[s * 32768 + q]);
    }
}

// ---------------- aggregation v3: one node per 16-lane group, lane = 8 features --------------
// One global_load_dwordx4 serves 4 edges (one per group). Inner j-loop is a
// compile-time 16-trip unroll -> 16 independent gathers in flight per wave.
__global__ __launch_bounds__(256) void k_agg(
    const unsigned int* __restrict__ h,        // [(N+1)][64] packed bf16x2 (row N = zeros)
    const int* __restrict__ offs,              // [N+1] padded offsets
    const int* __restrict__ keys,              // padded packed keys
    const float* __restrict__ e1l, const float* __restrict__ e2l,
    unsigned int* __restrict__ agg)            // [NPAD][64] packed bf16x2
{
    __shared__ float e12[22 * 132];            // stride 132 spreads group reads across banks
    for (int t = threadIdx.x; t < 22 * 128; t += 256) {
        int combo = t >> 7, f = t & 127;
        float v = 0.f;
        if (combo < 21) {
            int a0 = combo / 3, a1 = combo - a0 * 3;
            v = e1l[a0 * EMB + f] + e2l[a1 * EMB + f];
        }
        e12[combo * 132 + f] = v;
    }
    __syncthreads();
    int wave = threadIdx.x >> 6, lane = threadIdx.x & 63;
    int sub = lane >> 4, fl = lane & 15;
    int node = blockIdx.x * 16 + wave * 4 + sub;
    float ax[8] = {0.f, 0.f, 0.f, 0.f, 0.f, 0.f, 0.f, 0.f};
    int o = 0, nch = 0;
    if (node < N_NODES) {
        o = offs[node];
        nch = (offs[node + 1] - o) >> 4;
        // self loop: attr=[4,0] -> combo 12
        uint4 hv = *(const uint4*)(h + (size_t)node * 64 + fl * 4);
        const float* ep = e12 + 12 * 132 + fl * 8;
        float4 e0 = *(const float4*)ep, e1_ = *(const float4*)(ep + 4);
        ax[0] = bflo(hv.x) + e0.x;  ax[1] = bfhi(hv.x) + e0.y;
        ax[2] = bflo(hv.y) + e0.z;  ax[3] = bfhi(hv.y) + e0.w;
        ax[4] = bflo(hv.z) + e1_.x; ax[5] = bfhi(hv.z) + e1_.y;
        ax[6] = bflo(hv.w) + e1_.z; ax[7] = bfhi(hv.w) + e1_.w;
    }
    int maxch = nch;
#pragma unroll
    for (int d = 32; d; d >>= 1) maxch = max(maxch, __shfl_xor(maxch, d));
    for (int c = 0; c < maxch; ++c) {
        int key = SENT_KEY;
        if (c < nch) key = keys[o + c * 16 + fl];
#pragma unroll
        for (int j = 0; j < 16; ++j) {
            int kj = __shfl(key, sub * 16 + j);
            uint4 g = *(const uint4*)(h + (size_t)(kj >> 5) * 64 + fl * 4);
            const float* ep = e12 + (kj & 31) * 132 + fl * 8;
            float4 e0 = *(const float4*)ep, e1_ = *(const float4*)(ep + 4);
            ax[0] += bflo(g.x) + e0.x;  ax[1] += bfhi(g.x) + e0.y;
            ax[2] += bflo(g.y) + e0.z;  ax[3] += bfhi(g.y) + e0.w;
            ax[4] += bflo(g.z) + e1_.x; ax[5] += bfhi(g.z) + e1_.y;
            ax[6] += bflo(g.w) + e1_.z; ax[7] += bfhi(g.w) + e1_.w;
        }
    }
    if (node < NPAD) {
        uint4 out;
        out.x = packbf(ax[0], ax[1]); out.y = packbf(ax[2], ax[3]);
        out.z = packbf(ax[4], ax[5]); out.w = packbf(ax[6], ax[7]);
        *(uint4*)(agg + (size_t)node * 64 + fl * 4) = out;   // pad rows -> zeros
    }
}

// ---------------- fused MLP: h2 = relu(agg@W1+b1)@W2+b2 ----------------
// h2 aliases agg (same buffer): each block reads only its own 64 rows and all
// reads complete (via the LDS round-trip) before its stores. No __restrict__.
__global__ __launch_bounds__(256) void k_mlp(
    unsigned short* aggh2,                     // [NPAD][128] bf16 in, [N][128] bf16 out
    const unsigned short* __restrict__ w1t,    // [256][128]  (W1 transposed: [n][k])
    const float* __restrict__ b1,              // [256]
    const unsigned short* __restrict__ w2t,    // [128][256]  (W2 transposed: [n][k])
    const float* __restrict__ b2)              // [128]
{
    __shared__ __align__(16) short tl[4][16][264];   // per-wave 16x256 t tile, padded stride
    int wave = threadIdx.x >> 6, lane = threadIdx.x & 63;
    int quad = lane >> 4, r16 = lane & 15;
    int m0 = (blockIdx.x * 4 + wave) * 16;

    // A fragments for GEMM1: A[m=r16][k=quad*8+j], 4 K-chunks of 32
    const unsigned short* arow = aggh2 + (size_t)(m0 + r16) * 128 + quad * 8;
    short8 af[4];
#pragma unroll
    for (int c = 0; c < 4; ++c) af[c] = *(const short8*)(arow + c * 32);

    // GEMM1 + bias + relu -> LDS
#pragma unroll
    for (int nt = 0; nt < 16; ++nt) {
        f32x4 acc = {0.f, 0.f, 0.f, 0.f};
        const unsigned short* brow = w1t + (nt * 16 + r16) * 128 + quad * 8;
#pragma unroll
        for (int c = 0; c < 4; ++c)
            acc = __builtin_amdgcn_mfma_f32_16x16x32_bf16(af[c], *(const short8*)(brow + c * 32), acc, 0, 0, 0);
        float bv = b1[nt * 16 + r16];   // bias along col = r16
#pragma unroll
        for (int r = 0; r < 4; ++r) {
            float v = acc[r] + bv;
            v = v > 0.f ? v : 0.f;
            tl[wave][quad * 4 + r][nt * 16 + r16] = (short)f2bf(v);
        }
    }
    __syncthreads();

    // GEMM2: A = t (LDS), 8 K-chunks of 32 over K=256, 8 N-tiles over 128
    f32x4 acc2[8];
#pragma unroll
    for (int nt = 0; nt < 8; ++nt) acc2[nt] = (f32x4){0.f, 0.f, 0.f, 0.f};
#pragma unroll
    for (int c2 = 0; c2 < 8; ++c2) {
        short8 a2 = *(const short8*)(&tl[wave][r16][c2 * 32 + quad * 8]);
#pragma unroll
        for (int nt = 0; nt < 8; ++nt) {
            short8 bfrag = *(const short8*)(w2t + (nt * 16 + r16) * 256 + c2 * 32 + quad * 8);
            acc2[nt] = __builtin_amdgcn_mfma_f32_16x16x32_bf16(a2, bfrag, acc2[nt], 0, 0, 0);
        }
    }
#pragma unroll
    for (int nt = 0; nt < 8; ++nt) {
        float bv = b2[nt * 16 + r16];
#pragma unroll
        for (int r = 0; r < 4; ++r) {
            int row = m0 + quad * 4 + r;
            if (row < N_NODES) aggh2[(size_t)row * 128 + nt * 16 + r16] = f2bf(acc2[nt][r] + bv);
        }
    }
}

// ---------------- BN stats: per-column sum & sumsq (fp32), LDS-reduced, 250 blocks ----------------
__global__ void k_bnstats(const unsigned int* __restrict__ h2, float* __restrict__ cs) {
    __shared__ float4 sm[256];
    int p = threadIdx.x & 63;                  // column pair
    int g = threadIdx.x >> 6;                  // 0..3
    int r0 = blockIdx.x * 200;                 // 250 blocks x 200 rows = 50000
    float s0 = 0.f, s1 = 0.f, q0 = 0.f, q1 = 0.f;
    for (int r = r0 + g; r < r0 + 200; r += 4) {
        unsigned int v = h2[(size_t)r * 64 + p];
        float a = bflo(v), b = bfhi(v);
        s0 += a; q0 += a * a;
        s1 += b; q1 += b * b;
    }
    sm[threadIdx.x] = make_float4(s0, s1, q0, q1);
    __syncthreads();
    if (threadIdx.x < 64) {
        float4 a = sm[p], b = sm[p + 64], c = sm[p + 128], d = sm[p + 192];
        atomicAdd(&cs[2 * p],       a.x + b.x + c.x + d.x);
        atomicAdd(&cs[2 * p + 1],   a.y + b.y + c.y + d.y);
        atomicAdd(&cs[128 + 2 * p],     a.z + b.z + c.z + d.z);
        atomicAdd(&cs[128 + 2 * p + 1], a.w + b.w + c.w + d.w);
    }
}

// ---------------- BN normalize (+relu for layer 0 -> bf16 h; layer 1 -> fp32 d_out) ----------------
__global__ void k_bnnorm(const unsigned int* __restrict__ h2, const float* __restrict__ cs,
                         const float* __restrict__ gamma, const float* __restrict__ beta,
                         unsigned int* __restrict__ outb, float2* __restrict__ outf, int mode) {
    int idx = blockIdx.x * 256 + threadIdx.x;  // [0, N*64)
    if (idx >= N_NODES * 64) return;
    int p = idx & 63;
    int c0 = 2 * p, c1 = 2 * p + 1;
    float m0 = cs[c0] * (1.f / N_NODES);
    float m1 = cs[c1] * (1.f / N_NODES);
    float v0 = cs[128 + c0] * (1.f / N_NODES) - m0 * m0;
    float v1 = cs[128 + c1] * (1.f / N_NODES) - m1 * m1;
    float r0 = rsqrtf(v0 + BN_EPS), r1 = rsqrtf(v1 + BN_EPS);
    unsigned int hv = h2[idx];
    float a = (bflo(hv) - m0) * r0 * gamma[c0] + beta[c0];
    float b = (bfhi(hv) - m1) * r1 * gamma[c1] + beta[c1];
    if (mode == 0) {
        a = a > 0.f ? a : 0.f;
        b = b > 0.f ? b : 0.f;
        outb[idx] = packbf(a, b);
    } else {
        outf[idx] = make_float2(a, b);
    }
}

extern "C" void kernel_launch(void* const* d_in, const int* in_sizes, int n_in,
                              void* d_out, int out_size, void* d_ws, size_t ws_size,
                              hipStream_t stream) {
    const int* x  = (const int*)d_in[0];
    const int* ei = (const int*)d_in[1];
    const int* ea = (const int*)d_in[2];
    // d_in[3] = batch (unused)
    const float* xe1 = (const float*)d_in[4];
    const float* xe2 = (const float*)d_in[5];
    const float* e1  = (const float*)d_in[6];   // [2][7][128]
    const float* e2  = (const float*)d_in[7];   // [2][3][128]
    const float* W1  = (const float*)d_in[8];   // [2][128][256]
    const float* b1  = (const float*)d_in[9];   // [2][256]
    const float* W2  = (const float*)d_in[10];  // [2][256][128]
    const float* b2  = (const float*)d_in[11];  // [2][128]
    const float* gm  = (const float*)d_in[12];  // [2][128]
    const float* bt  = (const float*)d_in[13];  // [2][128]

    char* ws = (char*)d_ws;
    size_t off = 0;
    auto take = [&](size_t bytes) -> char* {
        char* p = ws + off;
        off = (off + bytes + 255) & ~(size_t)255;
        return p;
    };
    unsigned int* h_buf = (unsigned int*)take((size_t)(N_NODES + 1) * 64 * 4); // +1 zero row
    unsigned int* aggb  = (unsigned int*)take((size_t)NPAD * 64 * 4);          // agg, then h2
    unsigned short* w1t = (unsigned short*)take((size_t)2 * 32768 * 2);
    unsigned short* w2t = (unsigned short*)take((size_t)2 * 32768 * 2);
    int* deg    = (int*)take((size_t)N_NODES * 4);
    int* offs   = (int*)take((size_t)(N_NODES + 1) * 4);
    int* cursor = (int*)take((size_t)N_NODES * 4);
    int* keys   = (int*)take((size_t)(N_EDGES + N_NODES * 16) * 4);
    int* bsums  = (int*)take(64 * 4);
    float* cs   = (float*)take(512 * 4);

    k_embed<<<((N_NODES + 1) * 64 + 255) / 256, 256, 0, stream>>>(x, xe1, xe2, h_buf);
    k_zero2<<<(N_NODES + 255) / 256, 256, 0, stream>>>(deg, cs);
    k_hist<<<(N_EDGES + 255) / 256, 256, 0, stream>>>(ei + N_EDGES, deg);
    k_scan1<<<49, 1024, 0, stream>>>(deg, offs, bsums);   // offs used as 'part' scratch here
    k_scan2<<<1, 64, 0, stream>>>(bsums, 49);
    k_scan3<<<(N_NODES + 255) / 256, 256, 0, stream>>>(offs, bsums, deg, offs, cursor);
    k_fill<<<(N_EDGES + 255) / 256, 256, 0, stream>>>(ei, ea, cursor, keys);
    k_pad<<<(N_NODES * 16 + 255) / 256, 256, 0, stream>>>(offs, deg, keys);
    k_transpose4<<<512, 256, 0, stream>>>(W1, W2, w1t, w2t);

    for (int l = 0; l < 2; ++l) {
        k_agg<<<NPAD / 16, 256, 0, stream>>>(h_buf, offs, keys,
                                             e1 + l * 896, e2 + l * 384, aggb);
        k_mlp<<<NPAD / 64, 256, 0, stream>>>((unsigned short*)aggb, w1t + l * 32768, b1 + l * 256,
                                             w2t + l * 32768, b2 + l * 128);
        k_bnstats<<<250, 256, 0, stream>>>(aggb, cs + l * 256);
        k_bnnorm<<<(N_NODES * 64) / 256, 256, 0, stream>>>(aggb, cs + l * 256, gm + l * 128, bt + l * 128,
                                                           h_buf, (float2*)d_out, l);
    }
}

// Round 5
// 421.902 us; speedup vs baseline: 1.7294x; 1.1562x over previous
//
#include <hip/hip_runtime.h>
#include <stdint.h>

#define N_NODES 50000
#define N_EDGES 800000
#define EMB 128
#define NPAD 50176        // padded to multiple of 128 rows for MLP (392 blocks x 128)
#define BN_EPS 1e-5f
#define SENT_KEY ((N_NODES << 5) | 21)   // sentinel: zero h-row, zero e12 entry

typedef __attribute__((ext_vector_type(8))) short short8;
typedef __attribute__((ext_vector_type(4))) float f32x4;

__device__ __forceinline__ float bf2f(unsigned short u) {
    return __uint_as_float(((unsigned int)u) << 16);
}
__device__ __forceinline__ unsigned short f2bf(float f) {
    unsigned int u = __float_as_uint(f);
    u += 0x7fffu + ((u >> 16) & 1u);   // RNE; values finite
    return (unsigned short)(u >> 16);
}
__device__ __forceinline__ float bflo(unsigned int v) { return __uint_as_float(v << 16); }
__device__ __forceinline__ float bfhi(unsigned int v) { return __uint_as_float(v & 0xffff0000u); }
__device__ __forceinline__ unsigned int packbf(float lo, float hi) {
    return (unsigned int)f2bf(lo) | ((unsigned int)f2bf(hi) << 16);
}

// ---------------- embedding (fp32 in, bf16x2 out); also writes the zero sentinel row ----------
__global__ void k_embed(const int* __restrict__ x, const float* __restrict__ xe1,
                        const float* __restrict__ xe2, unsigned int* __restrict__ h) {
    int idx = blockIdx.x * 256 + threadIdx.x;   // [0, (N+1)*64)
    int i = idx >> 6, j = idx & 63;
    if (i > N_NODES) return;
    if (i == N_NODES) { h[(size_t)i * 64 + j] = 0u; return; }
    int a = x[2 * i], c = x[2 * i + 1];
    float2 va = *(const float2*)(xe1 + a * EMB + j * 2);
    float2 vb = *(const float2*)(xe2 + c * EMB + j * 2);
    h[i * 64 + j] = packbf(va.x + vb.x, va.y + vb.y);
}

// zero deg[N_NODES] and cs[512] in one launch
__global__ void k_zero2(int* __restrict__ deg, float* __restrict__ cs) {
    int i = blockIdx.x * 256 + threadIdx.x;
    if (i < N_NODES) deg[i] = 0;
    if (i < 512) cs[i] = 0.f;
}

// ---------------- CSR build (padded-to-16 per node, with packed keys) ----------------
__global__ void k_hist(const int* __restrict__ dst, int* __restrict__ deg) {
    int e = blockIdx.x * 256 + threadIdx.x;
    if (e < N_EDGES) atomicAdd(&deg[dst[e]], 1);
}

// scan over PADDED degrees: pdeg = ceil(deg/16)*16
__global__ void k_scan1(const int* __restrict__ deg, int* __restrict__ part, int* __restrict__ bsums) {
    __shared__ int sm[1024];
    int i = blockIdx.x * 1024 + threadIdx.x;
    int d = (i < N_NODES) ? deg[i] : 0;
    int v = (d + 15) & ~15;
    sm[threadIdx.x] = v;
    __syncthreads();
    for (int off = 1; off < 1024; off <<= 1) {
        int t = (threadIdx.x >= off) ? sm[threadIdx.x - off] : 0;
        __syncthreads();
        sm[threadIdx.x] += t;
        __syncthreads();
    }
    if (i < N_NODES) part[i] = sm[threadIdx.x] - v;   // exclusive within block
    if (threadIdx.x == 1023) bsums[blockIdx.x] = sm[1023];
}

// one-wave shuffle prefix scan over <=64 block sums
__global__ void k_scan2(int* __restrict__ bsums, int nb) {
    int lane = threadIdx.x;
    int v = (lane < nb) ? bsums[lane] : 0;
    int orig = v;
    for (int off = 1; off < 64; off <<= 1) {
        int t = __shfl_up(v, off);
        if (lane >= off) v += t;
    }
    if (lane < nb) bsums[lane] = v - orig;   // exclusive
}

__global__ void k_scan3(const int* __restrict__ part, const int* __restrict__ bsums,
                        const int* __restrict__ deg, int* __restrict__ offs,
                        int* __restrict__ cursor) {
    int i = blockIdx.x * 256 + threadIdx.x;
    if (i >= N_NODES) return;
    int o = part[i] + bsums[i >> 10];
    offs[i] = o;
    cursor[i] = o;
    if (i == N_NODES - 1) offs[N_NODES] = o + ((deg[i] + 15) & ~15);
}

// fill packed keys: key = (src<<5) | (a0*3+a1)
__global__ void k_fill(const int* __restrict__ ei, const int* __restrict__ ea,
                       int* __restrict__ cursor, int* __restrict__ keys) {
    int e = blockIdx.x * 256 + threadIdx.x;
    if (e >= N_EDGES) return;
    int d = ei[N_EDGES + e];
    int s = ei[e];
    int a0 = ea[2 * e], a1 = ea[2 * e + 1];
    int p = atomicAdd(&cursor[d], 1);
    keys[p] = (s << 5) | (a0 * 3 + a1);
}

// pad each node's key list up to its padded length with sentinels (pad < 16)
__global__ void k_pad(const int* __restrict__ offs, const int* __restrict__ deg,
                      int* __restrict__ keys) {
    int idx = blockIdx.x * 256 + threadIdx.x;
    int i = idx >> 4, j = idx & 15;
    if (i >= N_NODES) return;
    int p = offs[i] + deg[i] + j;
    if (p < offs[i + 1]) keys[p] = SENT_KEY;
}

// ---------------- fused weight transpose+cast: both layers, both weights ----------------
__global__ void k_transpose4(const float* __restrict__ W1, const float* __restrict__ W2,
                             unsigned short* __restrict__ w1t, unsigned short* __restrict__ w2t) {
    int idx = blockIdx.x * 256 + threadIdx.x;   // [0, 4*32768)
    int sec = idx >> 15, q = idx & 32767;
    if (sec < 2) {           // W1[sec]: [128][256] -> w1t[sec][c*128+r]
        int r = q >> 8, c = q & 255;
        w1t[sec * 32768 + c * 128 + r] = f2bf(W1[sec * 32768 + q]);
    } else {                 // W2[sec-2]: [256][128] -> w2t[sec-2][c*256+r]
        int s = sec - 2;
        int r = q >> 7, c = q & 127;
        w2t[s * 32768 + c * 256 + r] = f2bf(W2[s * 32768 + q]);
    }
}

// ---------------- aggregation v3: one node per 16-lane group, lane = 8 features --------------
// One global_load_dwordx4 serves 4 edges (one per group). Inner j-loop is a
// compile-time 16-trip unroll -> 16 independent gathers in flight per wave.
__global__ __launch_bounds__(256) void k_agg(
    const unsigned int* __restrict__ h,        // [(N+1)][64] packed bf16x2 (row N = zeros)
    const int* __restrict__ offs,              // [N+1] padded offsets
    const int* __restrict__ keys,              // padded packed keys
    const float* __restrict__ e1l, const float* __restrict__ e2l,
    unsigned int* __restrict__ agg)            // [NPAD][64] packed bf16x2
{
    __shared__ float e12[22 * 132];            // stride 132 spreads group reads across banks
    for (int t = threadIdx.x; t < 22 * 128; t += 256) {
        int combo = t >> 7, f = t & 127;
        float v = 0.f;
        if (combo < 21) {
            int a0 = combo / 3, a1 = combo - a0 * 3;
            v = e1l[a0 * EMB + f] + e2l[a1 * EMB + f];
        }
        e12[combo * 132 + f] = v;
    }
    __syncthreads();
    int wave = threadIdx.x >> 6, lane = threadIdx.x & 63;
    int sub = lane >> 4, fl = lane & 15;
    int node = blockIdx.x * 16 + wave * 4 + sub;
    float ax[8] = {0.f, 0.f, 0.f, 0.f, 0.f, 0.f, 0.f, 0.f};
    int o = 0, nch = 0;
    if (node < N_NODES) {
        o = offs[node];
        nch = (offs[node + 1] - o) >> 4;
        // self loop: attr=[4,0] -> combo 12
        uint4 hv = *(const uint4*)(h + (size_t)node * 64 + fl * 4);
        const float* ep = e12 + 12 * 132 + fl * 8;
        float4 e0 = *(const float4*)ep, e1_ = *(const float4*)(ep + 4);
        ax[0] = bflo(hv.x) + e0.x;  ax[1] = bfhi(hv.x) + e0.y;
        ax[2] = bflo(hv.y) + e0.z;  ax[3] = bfhi(hv.y) + e0.w;
        ax[4] = bflo(hv.z) + e1_.x; ax[5] = bfhi(hv.z) + e1_.y;
        ax[6] = bflo(hv.w) + e1_.z; ax[7] = bfhi(hv.w) + e1_.w;
    }
    int maxch = nch;
#pragma unroll
    for (int d = 32; d; d >>= 1) maxch = max(maxch, __shfl_xor(maxch, d));
    for (int c = 0; c < maxch; ++c) {
        int key = SENT_KEY;
        if (c < nch) key = keys[o + c * 16 + fl];
#pragma unroll
        for (int j = 0; j < 16; ++j) {
            int kj = __shfl(key, sub * 16 + j);
            uint4 g = *(const uint4*)(h + (size_t)(kj >> 5) * 64 + fl * 4);
            const float* ep = e12 + (kj & 31) * 132 + fl * 8;
            float4 e0 = *(const float4*)ep, e1_ = *(const float4*)(ep + 4);
            ax[0] += bflo(g.x) + e0.x;  ax[1] += bfhi(g.x) + e0.y;
            ax[2] += bflo(g.y) + e0.z;  ax[3] += bfhi(g.y) + e0.w;
            ax[4] += bflo(g.z) + e1_.x; ax[5] += bfhi(g.z) + e1_.y;
            ax[6] += bflo(g.w) + e1_.z; ax[7] += bfhi(g.w) + e1_.w;
        }
    }
    if (node < NPAD) {
        uint4 out;
        out.x = packbf(ax[0], ax[1]); out.y = packbf(ax[2], ax[3]);
        out.z = packbf(ax[4], ax[5]); out.w = packbf(ax[6], ax[7]);
        *(uint4*)(agg + (size_t)node * 64 + fl * 4) = out;   // pad rows -> zeros
    }
}

// ---------------- fused MLP v2: h2 = relu(agg@W1+b1)@W2+b2, no LDS ----------------
// GEMM1 computed operand-swapped (A=w1 frag, B=agg frag) so D comes out
// t-TRANSPOSED in C-layout: lane(quad,r16) holds t[k2=nt*16+quad*4+r][node=r16].
// 8 shuffles + 4 selects convert that to GEMM2's A-fragment (8 consecutive k2
// for node=lane&15) -- no LDS round-trip, no barriers. M=32 rows/wave register
// blocking: agg B-frags live in regs all kernel; every weight fragment feeds
// 2 MFMAs. h2 aliases agg: each wave reads only its own 32 rows (at start)
// and stores them at the end; waves are row-disjoint.
__global__ __launch_bounds__(256, 2) void k_mlp(
    unsigned short* aggh2,                     // [NPAD][128] bf16 in, [N][128] bf16 out
    const unsigned short* __restrict__ w1t,    // [256][128]  (W1 transposed: [n][k])
    const float* __restrict__ b1,              // [256]
    const unsigned short* __restrict__ w2t,    // [128][256]  (W2 transposed: [n][k])
    const float* __restrict__ b2)              // [128]
{
    int lane = threadIdx.x & 63;
    int wave = threadIdx.x >> 6;
    int quad = lane >> 4, r16 = lane & 15;
    int m0 = (blockIdx.x * 4 + wave) * 32;     // 32 rows per wave
    int sel  = (lane >> 5) & 1;                // which nt tile my A2 comes from
    int srcA = ((lane >> 4) & 1) * 32 + r16;   // source lane for j=0..3
    int srcB = srcA + 16;                      // source lane for j=4..7

    // agg B-frags (GEMM1 swapped): B[k=quad*8+j][node=r16]
    short8 bagg[2][4];
#pragma unroll
    for (int t = 0; t < 2; ++t)
#pragma unroll
        for (int c = 0; c < 4; ++c)
            bagg[t][c] = *(const short8*)(aggh2 + (size_t)(m0 + t * 16 + r16) * 128 + c * 32 + quad * 8);

    float b2v[8];
#pragma unroll
    for (int n = 0; n < 8; ++n) b2v[n] = b2[n * 16 + r16];

    f32x4 acc2[2][8];
#pragma unroll
    for (int t = 0; t < 2; ++t)
#pragma unroll
        for (int n = 0; n < 8; ++n) acc2[t][n] = (f32x4){0.f, 0.f, 0.f, 0.f};

    for (int c2 = 0; c2 < 8; ++c2) {
        unsigned int pk[2][2][2];              // [ntl][tile][dword]
#pragma unroll
        for (int ntl = 0; ntl < 2; ++ntl) {
            int nt = c2 * 2 + ntl;
            short8 aw[4];
#pragma unroll
            for (int c = 0; c < 4; ++c)
                aw[c] = *(const short8*)(w1t + (nt * 16 + r16) * 128 + c * 32 + quad * 8);
            float4 bv = *(const float4*)(b1 + nt * 16 + quad * 4);
#pragma unroll
            for (int t = 0; t < 2; ++t) {
                f32x4 a1 = {0.f, 0.f, 0.f, 0.f};
#pragma unroll
                for (int c = 0; c < 4; ++c)
                    a1 = __builtin_amdgcn_mfma_f32_16x16x32_bf16(aw[c], bagg[t][c], a1, 0, 0, 0);
                float v0 = a1[0] + bv.x; v0 = v0 > 0.f ? v0 : 0.f;
                float v1 = a1[1] + bv.y; v1 = v1 > 0.f ? v1 : 0.f;
                float v2 = a1[2] + bv.z; v2 = v2 > 0.f ? v2 : 0.f;
                float v3 = a1[3] + bv.w; v3 = v3 > 0.f ? v3 : 0.f;
                pk[ntl][t][0] = packbf(v0, v1);
                pk[ntl][t][1] = packbf(v2, v3);
            }
        }
        short8 a2f[2];
#pragma unroll
        for (int t = 0; t < 2; ++t) {
            int u0 = __shfl((int)pk[0][t][0], srcA), w0 = __shfl((int)pk[1][t][0], srcA);
            int u1 = __shfl((int)pk[0][t][1], srcA), w1_ = __shfl((int)pk[1][t][1], srcA);
            int u2 = __shfl((int)pk[0][t][0], srcB), w2_ = __shfl((int)pk[1][t][0], srcB);
            int u3 = __shfl((int)pk[0][t][1], srcB), w3_ = __shfl((int)pk[1][t][1], srcB);
            union { int i[4]; short8 s; } a2u;
            a2u.i[0] = sel ? w0 : u0;
            a2u.i[1] = sel ? w1_ : u1;
            a2u.i[2] = sel ? w2_ : u2;
            a2u.i[3] = sel ? w3_ : u3;
            a2f[t] = a2u.s;
        }
#pragma unroll
        for (int n = 0; n < 8; ++n) {
            short8 bw = *(const short8*)(w2t + (n * 16 + r16) * 256 + c2 * 32 + quad * 8);
            acc2[0][n] = __builtin_amdgcn_mfma_f32_16x16x32_bf16(a2f[0], bw, acc2[0][n], 0, 0, 0);
            acc2[1][n] = __builtin_amdgcn_mfma_f32_16x16x32_bf16(a2f[1], bw, acc2[1][n], 0, 0, 0);
        }
    }
#pragma unroll
    for (int t = 0; t < 2; ++t)
#pragma unroll
        for (int n = 0; n < 8; ++n)
#pragma unroll
            for (int r = 0; r < 4; ++r) {
                int row = m0 + t * 16 + quad * 4 + r;
                if (row < N_NODES)
                    aggh2[(size_t)row * 128 + n * 16 + r16] = f2bf(acc2[t][n][r] + b2v[n]);
            }
}

// ---------------- BN stats: per-column sum & sumsq (fp32), LDS-reduced, 250 blocks ----------------
__global__ void k_bnstats(const unsigned int* __restrict__ h2, float* __restrict__ cs) {
    __shared__ float4 sm[256];
    int p = threadIdx.x & 63;                  // column pair
    int g = threadIdx.x >> 6;                  // 0..3
    int r0 = blockIdx.x * 200;                 // 250 blocks x 200 rows = 50000
    float s0 = 0.f, s1 = 0.f, q0 = 0.f, q1 = 0.f;
    for (int r = r0 + g; r < r0 + 200; r += 4) {
        unsigned int v = h2[(size_t)r * 64 + p];
        float a = bflo(v), b = bfhi(v);
        s0 += a; q0 += a * a;
        s1 += b; q1 += b * b;
    }
    sm[threadIdx.x] = make_float4(s0, s1, q0, q1);
    __syncthreads();
    if (threadIdx.x < 64) {
        float4 a = sm[p], b = sm[p + 64], c = sm[p + 128], d = sm[p + 192];
        atomicAdd(&cs[2 * p],       a.x + b.x + c.x + d.x);
        atomicAdd(&cs[2 * p + 1],   a.y + b.y + c.y + d.y);
        atomicAdd(&cs[128 + 2 * p],     a.z + b.z + c.z + d.z);
        atomicAdd(&cs[128 + 2 * p + 1], a.w + b.w + c.w + d.w);
    }
}

// ---------------- BN normalize (+relu for layer 0 -> bf16 h; layer 1 -> fp32 d_out) ----------------
__global__ void k_bnnorm(const unsigned int* __restrict__ h2, const float* __restrict__ cs,
                         const float* __restrict__ gamma, const float* __restrict__ beta,
                         unsigned int* __restrict__ outb, float2* __restrict__ outf, int mode) {
    int idx = blockIdx.x * 256 + threadIdx.x;  // [0, N*64)
    if (idx >= N_NODES * 64) return;
    int p = idx & 63;
    int c0 = 2 * p, c1 = 2 * p + 1;
    float m0 = cs[c0] * (1.f / N_NODES);
    float m1 = cs[c1] * (1.f / N_NODES);
    float v0 = cs[128 + c0] * (1.f / N_NODES) - m0 * m0;
    float v1 = cs[128 + c1] * (1.f / N_NODES) - m1 * m1;
    float r0 = rsqrtf(v0 + BN_EPS), r1 = rsqrtf(v1 + BN_EPS);
    unsigned int hv = h2[idx];
    float a = (bflo(hv) - m0) * r0 * gamma[c0] + beta[c0];
    float b = (bfhi(hv) - m1) * r1 * gamma[c1] + beta[c1];
    if (mode == 0) {
        a = a > 0.f ? a : 0.f;
        b = b > 0.f ? b : 0.f;
        outb[idx] = packbf(a, b);
    } else {
        outf[idx] = make_float2(a, b);
    }
}

extern "C" void kernel_launch(void* const* d_in, const int* in_sizes, int n_in,
                              void* d_out, int out_size, void* d_ws, size_t ws_size,
                              hipStream_t stream) {
    const int* x  = (const int*)d_in[0];
    const int* ei = (const int*)d_in[1];
    const int* ea = (const int*)d_in[2];
    // d_in[3] = batch (unused)
    const float* xe1 = (const float*)d_in[4];
    const float* xe2 = (const float*)d_in[5];
    const float* e1  = (const float*)d_in[6];   // [2][7][128]
    const float* e2  = (const float*)d_in[7];   // [2][3][128]
    const float* W1  = (const float*)d_in[8];   // [2][128][256]
    const float* b1  = (const float*)d_in[9];   // [2][256]
    const float* W2  = (const float*)d_in[10];  // [2][256][128]
    const float* b2  = (const float*)d_in[11];  // [2][128]
    const float* gm  = (const float*)d_in[12];  // [2][128]
    const float* bt  = (const float*)d_in[13];  // [2][128]

    char* ws = (char*)d_ws;
    size_t off = 0;
    auto take = [&](size_t bytes) -> char* {
        char* p = ws + off;
        off = (off + bytes + 255) & ~(size_t)255;
        return p;
    };
    unsigned int* h_buf = (unsigned int*)take((size_t)(N_NODES + 1) * 64 * 4); // +1 zero row
    unsigned int* aggb  = (unsigned int*)take((size_t)NPAD * 64 * 4);          // agg, then h2
    unsigned short* w1t = (unsigned short*)take((size_t)2 * 32768 * 2);
    unsigned short* w2t = (unsigned short*)take((size_t)2 * 32768 * 2);
    int* deg    = (int*)take((size_t)N_NODES * 4);
    int* offs   = (int*)take((size_t)(N_NODES + 1) * 4);
    int* cursor = (int*)take((size_t)N_NODES * 4);
    int* keys   = (int*)take((size_t)(N_EDGES + N_NODES * 16) * 4);
    int* bsums  = (int*)take(64 * 4);
    float* cs   = (float*)take(512 * 4);

    k_embed<<<((N_NODES + 1) * 64 + 255) / 256, 256, 0, stream>>>(x, xe1, xe2, h_buf);
    k_zero2<<<(N_NODES + 255) / 256, 256, 0, stream>>>(deg, cs);
    k_hist<<<(N_EDGES + 255) / 256, 256, 0, stream>>>(ei + N_EDGES, deg);
    k_scan1<<<49, 1024, 0, stream>>>(deg, offs, bsums);   // offs used as 'part' scratch here
    k_scan2<<<1, 64, 0, stream>>>(bsums, 49);
    k_scan3<<<(N_NODES + 255) / 256, 256, 0, stream>>>(offs, bsums, deg, offs, cursor);
    k_fill<<<(N_EDGES + 255) / 256, 256, 0, stream>>>(ei, ea, cursor, keys);
    k_pad<<<(N_NODES * 16 + 255) / 256, 256, 0, stream>>>(offs, deg, keys);
    k_transpose4<<<512, 256, 0, stream>>>(W1, W2, w1t, w2t);

    for (int l = 0; l < 2; ++l) {
        k_agg<<<NPAD / 16, 256, 0, stream>>>(h_buf, offs, keys,
                                             e1 + l * 896, e2 + l * 384, aggb);
        k_mlp<<<NPAD / 128, 256, 0, stream>>>((unsigned short*)aggb, w1t + l * 32768, b1 + l * 256,
                                              w2t + l * 32768, b2 + l * 128);
        k_bnstats<<<250, 256, 0, stream>>>(aggb, cs + l * 256);
        k_bnnorm<<<(N_NODES * 64) / 256, 256, 0, stream>>>(aggb, cs + l * 256, gm + l * 128, bt + l * 128,
                                                           h_buf, (float2*)d_out, l);
    }
}

// Round 6
// 412.116 us; speedup vs baseline: 1.7704x; 1.0237x over previous
//
#include <hip/hip_runtime.h>
#include <stdint.h>

#define N_NODES 50000
#define N_EDGES 800000
#define EMB 128
#define NPAD 50176        // padded to multiple of 128 rows for MLP (392 blocks x 128)
#define BN_EPS 1e-5f
#define SENT_KEY ((N_NODES << 5) | 21)   // sentinel: zero h-row, zero e12 entry
#define NODES_PER_XCD 6250               // 50000 / 8
#define XCHUNK 2048
#define NCHUNKS ((N_EDGES + XCHUNK - 1) / XCHUNK)   // 391

typedef __attribute__((ext_vector_type(8))) short short8;
typedef __attribute__((ext_vector_type(4))) float f32x4;

__device__ __forceinline__ float bf2f(unsigned short u) {
    return __uint_as_float(((unsigned int)u) << 16);
}
__device__ __forceinline__ unsigned short f2bf(float f) {
    unsigned int u = __float_as_uint(f);
    u += 0x7fffu + ((u >> 16) & 1u);   // RNE; values finite
    return (unsigned short)(u >> 16);
}
__device__ __forceinline__ float bflo(unsigned int v) { return __uint_as_float(v << 16); }
__device__ __forceinline__ float bfhi(unsigned int v) { return __uint_as_float(v & 0xffff0000u); }
__device__ __forceinline__ unsigned int packbf(float lo, float hi) {
    return (unsigned int)f2bf(lo) | ((unsigned int)f2bf(hi) << 16);
}

// ---------------- embedding (fp32 in, bf16x2 out); also writes the zero sentinel row ----------
__global__ void k_embed(const int* __restrict__ x, const float* __restrict__ xe1,
                        const float* __restrict__ xe2, unsigned int* __restrict__ h) {
    int idx = blockIdx.x * 256 + threadIdx.x;   // [0, (N+1)*64)
    int i = idx >> 6, j = idx & 63;
    if (i > N_NODES) return;
    if (i == N_NODES) { h[(size_t)i * 64 + j] = 0u; return; }
    int a = x[2 * i], c = x[2 * i + 1];
    float2 va = *(const float2*)(xe1 + a * EMB + j * 2);
    float2 vb = *(const float2*)(xe2 + c * EMB + j * 2);
    h[i * 64 + j] = packbf(va.x + vb.x, va.y + vb.y);
}

// zero deg[N_NODES] and cs[512] in one launch
__global__ void k_zero2(int* __restrict__ deg, float* __restrict__ cs) {
    int i = blockIdx.x * 256 + threadIdx.x;
    if (i < N_NODES) deg[i] = 0;
    if (i < 512) cs[i] = 0.f;
}

// ---------------- CSR build (padded-to-16 per node, packed keys), XCD-partitioned -------------
// blockIdx&7 selects a dst-range; with the %8 block->XCD round-robin heuristic all
// atomics/stores for one deg/cursor/keys region come from one XCD: lines fill in
// that XCD's L2 instead of 64B-per-4B HBM writebacks. Mapping wrong => only slower,
// never incorrect.
__global__ void k_hist(const int* __restrict__ dst, int* __restrict__ deg) {
    int xcd = blockIdx.x & 7, chunk = blockIdx.x >> 3;
    int lo = xcd * NODES_PER_XCD, hi = lo + NODES_PER_XCD;
    int e0 = chunk * XCHUNK + threadIdx.x;
#pragma unroll
    for (int i = 0; i < XCHUNK / 256; ++i) {
        int e = e0 + i * 256;
        if (e < N_EDGES) {
            int d = dst[e];
            if (d >= lo && d < hi) atomicAdd(&deg[d], 1);
        }
    }
}

// scan over PADDED degrees: pdeg = ceil(deg/16)*16
__global__ void k_scan1(const int* __restrict__ deg, int* __restrict__ part, int* __restrict__ bsums) {
    __shared__ int sm[1024];
    int i = blockIdx.x * 1024 + threadIdx.x;
    int d = (i < N_NODES) ? deg[i] : 0;
    int v = (d + 15) & ~15;
    sm[threadIdx.x] = v;
    __syncthreads();
    for (int off = 1; off < 1024; off <<= 1) {
        int t = (threadIdx.x >= off) ? sm[threadIdx.x - off] : 0;
        __syncthreads();
        sm[threadIdx.x] += t;
        __syncthreads();
    }
    if (i < N_NODES) part[i] = sm[threadIdx.x] - v;   // exclusive within block
    if (threadIdx.x == 1023) bsums[blockIdx.x] = sm[1023];
}

// one-wave shuffle prefix scan over <=64 block sums
__global__ void k_scan2(int* __restrict__ bsums, int nb) {
    int lane = threadIdx.x;
    int v = (lane < nb) ? bsums[lane] : 0;
    int orig = v;
    for (int off = 1; off < 64; off <<= 1) {
        int t = __shfl_up(v, off);
        if (lane >= off) v += t;
    }
    if (lane < nb) bsums[lane] = v - orig;   // exclusive
}

__global__ void k_scan3(const int* __restrict__ part, const int* __restrict__ bsums,
                        const int* __restrict__ deg, int* __restrict__ offs,
                        int* __restrict__ cursor) {
    int i = blockIdx.x * 256 + threadIdx.x;
    if (i >= N_NODES) return;
    int o = part[i] + bsums[i >> 10];
    offs[i] = o;
    cursor[i] = o;
    if (i == N_NODES - 1) offs[N_NODES] = o + ((deg[i] + 15) & ~15);
}

// fill packed keys: key = (src<<5) | (a0*3+a1), XCD-partitioned like k_hist
__global__ void k_fill(const int* __restrict__ ei, const int* __restrict__ ea,
                       int* __restrict__ cursor, int* __restrict__ keys) {
    int xcd = blockIdx.x & 7, chunk = blockIdx.x >> 3;
    int lo = xcd * NODES_PER_XCD, hi = lo + NODES_PER_XCD;
    int e0 = chunk * XCHUNK + threadIdx.x;
#pragma unroll
    for (int i = 0; i < XCHUNK / 256; ++i) {
        int e = e0 + i * 256;
        if (e < N_EDGES) {
            int d = ei[N_EDGES + e];
            if (d >= lo && d < hi) {
                int s = ei[e];
                int a0 = ea[2 * e], a1 = ea[2 * e + 1];
                int p = atomicAdd(&cursor[d], 1);
                keys[p] = (s << 5) | (a0 * 3 + a1);
            }
        }
    }
}

// pad each node's key list up to its padded length with sentinels (pad < 16)
__global__ void k_pad(const int* __restrict__ offs, const int* __restrict__ deg,
                      int* __restrict__ keys) {
    int idx = blockIdx.x * 256 + threadIdx.x;
    int i = idx >> 4, j = idx & 15;
    if (i >= N_NODES) return;
    int p = offs[i] + deg[i] + j;
    if (p < offs[i + 1]) keys[p] = SENT_KEY;
}

// ---------------- fused weight transpose+cast: both layers, both weights ----------------
__global__ void k_transpose4(const float* __restrict__ W1, const float* __restrict__ W2,
                             unsigned short* __restrict__ w1t, unsigned short* __restrict__ w2t) {
    int idx = blockIdx.x * 256 + threadIdx.x;   // [0, 4*32768)
    int sec = idx >> 15, q = idx & 32767;
    if (sec < 2) {           // W1[sec]: [128][256] -> w1t[sec][c*128+r]
        int r = q >> 8, c = q & 255;
        w1t[sec * 32768 + c * 128 + r] = f2bf(W1[sec * 32768 + q]);
    } else {                 // W2[sec-2]: [256][128] -> w2t[sec-2][c*256+r]
        int s = sec - 2;
        int r = q >> 7, c = q & 127;
        w2t[s * 32768 + c * 256 + r] = f2bf(W2[s * 32768 + q]);
    }
}

// ---------------- aggregation v3: one node per 16-lane group, lane = 8 features --------------
// One global_load_dwordx4 serves 4 edges (one per group). Inner j-loop is a
// compile-time 16-trip unroll -> 16 independent gathers in flight per wave.
// Next-chunk key load is software-pipelined over the current chunk's gathers.
__global__ __launch_bounds__(256) void k_agg(
    const unsigned int* __restrict__ h,        // [(N+1)][64] packed bf16x2 (row N = zeros)
    const int* __restrict__ offs,              // [N+1] padded offsets
    const int* __restrict__ keys,              // padded packed keys
    const float* __restrict__ e1l, const float* __restrict__ e2l,
    unsigned int* __restrict__ agg)            // [NPAD][64] packed bf16x2
{
    __shared__ float e12[22 * 132];            // stride 132 spreads group reads across banks
    for (int t = threadIdx.x; t < 22 * 128; t += 256) {
        int combo = t >> 7, f = t & 127;
        float v = 0.f;
        if (combo < 21) {
            int a0 = combo / 3, a1 = combo - a0 * 3;
            v = e1l[a0 * EMB + f] + e2l[a1 * EMB + f];
        }
        e12[combo * 132 + f] = v;
    }
    __syncthreads();
    int wave = threadIdx.x >> 6, lane = threadIdx.x & 63;
    int sub = lane >> 4, fl = lane & 15;
    int node = blockIdx.x * 16 + wave * 4 + sub;
    float ax[8] = {0.f, 0.f, 0.f, 0.f, 0.f, 0.f, 0.f, 0.f};
    int o = 0, nch = 0;
    if (node < N_NODES) {
        o = offs[node];
        nch = (offs[node + 1] - o) >> 4;
        // self loop: attr=[4,0] -> combo 12
        uint4 hv = *(const uint4*)(h + (size_t)node * 64 + fl * 4);
        const float* ep = e12 + 12 * 132 + fl * 8;
        float4 e0 = *(const float4*)ep, e1_ = *(const float4*)(ep + 4);
        ax[0] = bflo(hv.x) + e0.x;  ax[1] = bfhi(hv.x) + e0.y;
        ax[2] = bflo(hv.y) + e0.z;  ax[3] = bfhi(hv.y) + e0.w;
        ax[4] = bflo(hv.z) + e1_.x; ax[5] = bfhi(hv.z) + e1_.y;
        ax[6] = bflo(hv.w) + e1_.z; ax[7] = bfhi(hv.w) + e1_.w;
    }
    int maxch = nch;
#pragma unroll
    for (int d = 32; d; d >>= 1) maxch = max(maxch, __shfl_xor(maxch, d));
    int key = (0 < nch) ? keys[o + fl] : SENT_KEY;
    for (int c = 0; c < maxch; ++c) {
        int keyn = (c + 1 < nch) ? keys[o + (c + 1) * 16 + fl] : SENT_KEY;
#pragma unroll
        for (int j = 0; j < 16; ++j) {
            int kj = __shfl(key, sub * 16 + j);
            uint4 g = *(const uint4*)(h + (size_t)(kj >> 5) * 64 + fl * 4);
            const float* ep = e12 + (kj & 31) * 132 + fl * 8;
            float4 e0 = *(const float4*)ep, e1_ = *(const float4*)(ep + 4);
            ax[0] += bflo(g.x) + e0.x;  ax[1] += bfhi(g.x) + e0.y;
            ax[2] += bflo(g.y) + e0.z;  ax[3] += bfhi(g.y) + e0.w;
            ax[4] += bflo(g.z) + e1_.x; ax[5] += bfhi(g.z) + e1_.y;
            ax[6] += bflo(g.w) + e1_.z; ax[7] += bfhi(g.w) + e1_.w;
        }
        key = keyn;
    }
    if (node < NPAD) {
        uint4 out;
        out.x = packbf(ax[0], ax[1]); out.y = packbf(ax[2], ax[3]);
        out.z = packbf(ax[4], ax[5]); out.w = packbf(ax[6], ax[7]);
        *(uint4*)(agg + (size_t)node * 64 + fl * 4) = out;   // pad rows -> zeros
    }
}

// ---------------- fused MLP v2: h2 = relu(agg@W1+b1)@W2+b2, no LDS ----------------
// GEMM1 computed operand-swapped (A=w1 frag, B=agg frag) so D comes out
// t-TRANSPOSED in C-layout: lane(quad,r16) holds t[k2=nt*16+quad*4+r][node=r16].
// 8 shuffles + 4 selects convert that to GEMM2's A-fragment -- no LDS, no barriers.
// M=32 rows/wave register blocking. h2 aliases agg: waves are row-disjoint.
__global__ __launch_bounds__(256, 2) void k_mlp(
    unsigned short* aggh2,                     // [NPAD][128] bf16 in, [N][128] bf16 out
    const unsigned short* __restrict__ w1t,    // [256][128]  (W1 transposed: [n][k])
    const float* __restrict__ b1,              // [256]
    const unsigned short* __restrict__ w2t,    // [128][256]  (W2 transposed: [n][k])
    const float* __restrict__ b2)              // [128]
{
    int lane = threadIdx.x & 63;
    int wave = threadIdx.x >> 6;
    int quad = lane >> 4, r16 = lane & 15;
    int m0 = (blockIdx.x * 4 + wave) * 32;     // 32 rows per wave
    int sel  = (lane >> 5) & 1;                // which nt tile my A2 comes from
    int srcA = ((lane >> 4) & 1) * 32 + r16;   // source lane for j=0..3
    int srcB = srcA + 16;                      // source lane for j=4..7

    // agg B-frags (GEMM1 swapped): B[k=quad*8+j][node=r16]
    short8 bagg[2][4];
#pragma unroll
    for (int t = 0; t < 2; ++t)
#pragma unroll
        for (int c = 0; c < 4; ++c)
            bagg[t][c] = *(const short8*)(aggh2 + (size_t)(m0 + t * 16 + r16) * 128 + c * 32 + quad * 8);

    float b2v[8];
#pragma unroll
    for (int n = 0; n < 8; ++n) b2v[n] = b2[n * 16 + r16];

    f32x4 acc2[2][8];
#pragma unroll
    for (int t = 0; t < 2; ++t)
#pragma unroll
        for (int n = 0; n < 8; ++n) acc2[t][n] = (f32x4){0.f, 0.f, 0.f, 0.f};

    for (int c2 = 0; c2 < 8; ++c2) {
        unsigned int pk[2][2][2];              // [ntl][tile][dword]
#pragma unroll
        for (int ntl = 0; ntl < 2; ++ntl) {
            int nt = c2 * 2 + ntl;
            short8 aw[4];
#pragma unroll
            for (int c = 0; c < 4; ++c)
                aw[c] = *(const short8*)(w1t + (nt * 16 + r16) * 128 + c * 32 + quad * 8);
            float4 bv = *(const float4*)(b1 + nt * 16 + quad * 4);
#pragma unroll
            for (int t = 0; t < 2; ++t) {
                f32x4 a1 = {0.f, 0.f, 0.f, 0.f};
#pragma unroll
                for (int c = 0; c < 4; ++c)
                    a1 = __builtin_amdgcn_mfma_f32_16x16x32_bf16(aw[c], bagg[t][c], a1, 0, 0, 0);
                float v0 = a1[0] + bv.x; v0 = v0 > 0.f ? v0 : 0.f;
                float v1 = a1[1] + bv.y; v1 = v1 > 0.f ? v1 : 0.f;
                float v2 = a1[2] + bv.z; v2 = v2 > 0.f ? v2 : 0.f;
                float v3 = a1[3] + bv.w; v3 = v3 > 0.f ? v3 : 0.f;
                pk[ntl][t][0] = packbf(v0, v1);
                pk[ntl][t][1] = packbf(v2, v3);
            }
        }
        short8 a2f[2];
#pragma unroll
        for (int t = 0; t < 2; ++t) {
            int u0 = __shfl((int)pk[0][t][0], srcA), w0 = __shfl((int)pk[1][t][0], srcA);
            int u1 = __shfl((int)pk[0][t][1], srcA), w1_ = __shfl((int)pk[1][t][1], srcA);
            int u2 = __shfl((int)pk[0][t][0], srcB), w2_ = __shfl((int)pk[1][t][0], srcB);
            int u3 = __shfl((int)pk[0][t][1], srcB), w3_ = __shfl((int)pk[1][t][1], srcB);
            union { int i[4]; short8 s; } a2u;
            a2u.i[0] = sel ? w0 : u0;
            a2u.i[1] = sel ? w1_ : u1;
            a2u.i[2] = sel ? w2_ : u2;
            a2u.i[3] = sel ? w3_ : u3;
            a2f[t] = a2u.s;
        }
#pragma unroll
        for (int n = 0; n < 8; ++n) {
            short8 bw = *(const short8*)(w2t + (n * 16 + r16) * 256 + c2 * 32 + quad * 8);
            acc2[0][n] = __builtin_amdgcn_mfma_f32_16x16x32_bf16(a2f[0], bw, acc2[0][n], 0, 0, 0);
            acc2[1][n] = __builtin_amdgcn_mfma_f32_16x16x32_bf16(a2f[1], bw, acc2[1][n], 0, 0, 0);
        }
    }
#pragma unroll
    for (int t = 0; t < 2; ++t)
#pragma unroll
        for (int n = 0; n < 8; ++n)
#pragma unroll
            for (int r = 0; r < 4; ++r) {
                int row = m0 + t * 16 + quad * 4 + r;
                if (row < N_NODES)
                    aggh2[(size_t)row * 128 + n * 16 + r16] = f2bf(acc2[t][n][r] + b2v[n]);
            }
}

// ---------------- BN stats: per-column sum & sumsq (fp32), LDS-reduced, 250 blocks ----------------
__global__ void k_bnstats(const unsigned int* __restrict__ h2, float* __restrict__ cs) {
    __shared__ float4 sm[256];
    int p = threadIdx.x & 63;                  // column pair
    int g = threadIdx.x >> 6;                  // 0..3
    int r0 = blockIdx.x * 200;                 // 250 blocks x 200 rows = 50000
    float s0 = 0.f, s1 = 0.f, q0 = 0.f, q1 = 0.f;
    for (int r = r0 + g; r < r0 + 200; r += 4) {
        unsigned int v = h2[(size_t)r * 64 + p];
        float a = bflo(v), b = bfhi(v);
        s0 += a; q0 += a * a;
        s1 += b; q1 += b * b;
    }
    sm[threadIdx.x] = make_float4(s0, s1, q0, q1);
    __syncthreads();
    if (threadIdx.x < 64) {
        float4 a = sm[p], b = sm[p + 64], c = sm[p + 128], d = sm[p + 192];
        atomicAdd(&cs[2 * p],       a.x + b.x + c.x + d.x);
        atomicAdd(&cs[2 * p + 1],   a.y + b.y + c.y + d.y);
        atomicAdd(&cs[128 + 2 * p],     a.z + b.z + c.z + d.z);
        atomicAdd(&cs[128 + 2 * p + 1], a.w + b.w + c.w + d.w);
    }
}

// ---------------- BN normalize (+relu for layer 0 -> bf16 h; layer 1 -> fp32 d_out) ----------------
__global__ void k_bnnorm(const unsigned int* __restrict__ h2, const float* __restrict__ cs,
                         const float* __restrict__ gamma, const float* __restrict__ beta,
                         unsigned int* __restrict__ outb, float2* __restrict__ outf, int mode) {
    int idx = blockIdx.x * 256 + threadIdx.x;  // [0, N*64)
    if (idx >= N_NODES * 64) return;
    int p = idx & 63;
    int c0 = 2 * p, c1 = 2 * p + 1;
    float m0 = cs[c0] * (1.f / N_NODES);
    float m1 = cs[c1] * (1.f / N_NODES);
    float v0 = cs[128 + c0] * (1.f / N_NODES) - m0 * m0;
    float v1 = cs[128 + c1] * (1.f / N_NODES) - m1 * m1;
    float r0 = rsqrtf(v0 + BN_EPS), r1 = rsqrtf(v1 + BN_EPS);
    unsigned int hv = h2[idx];
    float a = (bflo(hv) - m0) * r0 * gamma[c0] + beta[c0];
    float b = (bfhi(hv) - m1) * r1 * gamma[c1] + beta[c1];
    if (mode == 0) {
        a = a > 0.f ? a : 0.f;
        b = b > 0.f ? b : 0.f;
        outb[idx] = packbf(a, b);
    } else {
        outf[idx] = make_float2(a, b);
    }
}

extern "C" void kernel_launch(void* const* d_in, const int* in_sizes, int n_in,
                              void* d_out, int out_size, void* d_ws, size_t ws_size,
                              hipStream_t stream) {
    const int* x  = (const int*)d_in[0];
    const int* ei = (const int*)d_in[1];
    const int* ea = (const int*)d_in[2];
    // d_in[3] = batch (unused)
    const float* xe1 = (const float*)d_in[4];
    const float* xe2 = (const float*)d_in[5];
    const float* e1  = (const float*)d_in[6];   // [2][7][128]
    const float* e2  = (const float*)d_in[7];   // [2][3][128]
    const float* W1  = (const float*)d_in[8];   // [2][128][256]
    const float* b1  = (const float*)d_in[9];   // [2][256]
    const float* W2  = (const float*)d_in[10];  // [2][256][128]
    const float* b2  = (const float*)d_in[11];  // [2][128]
    const float* gm  = (const float*)d_in[12];  // [2][128]
    const float* bt  = (const float*)d_in[13];  // [2][128]

    char* ws = (char*)d_ws;
    size_t off = 0;
    auto take = [&](size_t bytes) -> char* {
        char* p = ws + off;
        off = (off + bytes + 255) & ~(size_t)255;
        return p;
    };
    unsigned int* h_buf = (unsigned int*)take((size_t)(N_NODES + 1) * 64 * 4); // +1 zero row
    unsigned int* aggb  = (unsigned int*)take((size_t)NPAD * 64 * 4);          // agg, then h2
    unsigned short* w1t = (unsigned short*)take((size_t)2 * 32768 * 2);
    unsigned short* w2t = (unsigned short*)take((size_t)2 * 32768 * 2);
    int* deg    = (int*)take((size_t)N_NODES * 4);
    int* offs   = (int*)take((size_t)(N_NODES + 1) * 4);
    int* cursor = (int*)take((size_t)N_NODES * 4);
    int* keys   = (int*)take((size_t)(N_EDGES + N_NODES * 16) * 4);
    int* bsums  = (int*)take(64 * 4);
    float* cs   = (float*)take(512 * 4);

    k_embed<<<((N_NODES + 1) * 64 + 255) / 256, 256, 0, stream>>>(x, xe1, xe2, h_buf);
    k_zero2<<<(N_NODES + 255) / 256, 256, 0, stream>>>(deg, cs);
    k_hist<<<8 * NCHUNKS, 256, 0, stream>>>(ei + N_EDGES, deg);
    k_scan1<<<49, 1024, 0, stream>>>(deg, offs, bsums);   // offs used as 'part' scratch here
    k_scan2<<<1, 64, 0, stream>>>(bsums, 49);
    k_scan3<<<(N_NODES + 255) / 256, 256, 0, stream>>>(offs, bsums, deg, offs, cursor);
    k_fill<<<8 * NCHUNKS, 256, 0, stream>>>(ei, ea, cursor, keys);
    k_pad<<<(N_NODES * 16 + 255) / 256, 256, 0, stream>>>(offs, deg, keys);
    k_transpose4<<<512, 256, 0, stream>>>(W1, W2, w1t, w2t);

    for (int l = 0; l < 2; ++l) {
        k_agg<<<NPAD / 16, 256, 0, stream>>>(h_buf, offs, keys,
                                             e1 + l * 896, e2 + l * 384, aggb);
        k_mlp<<<NPAD / 128, 256, 0, stream>>>((unsigned short*)aggb, w1t + l * 32768, b1 + l * 256,
                                              w2t + l * 32768, b2 + l * 128);
        k_bnstats<<<250, 256, 0, stream>>>(aggb, cs + l * 256);
        k_bnnorm<<<(N_NODES * 64) / 256, 256, 0, stream>>>(aggb, cs + l * 256, gm + l * 128, bt + l * 128,
                                                           h_buf, (float2*)d_out, l);
    }
}